// Round 8
// baseline (134.844 us; speedup 1.0000x reference)
//
#include <hip/hip_runtime.h>

// ---------------------------------------------------------------------------
// TransformerQuantizerRein on MI355X (gfx950)
// N=4, C=256, H=W=64 (S=4096 tokens), K=4096 codes.
//
//   logit[n][k][s] = sum_c' kWq[k][c'] * latent[n][c'][s] + kb[k]
//     kWq = (codebook @ (Wk^T @ Wq) + bk@Wq) / 64  (bf16, prescaled)
//     kb  = (codebook @ (Wk^T bq) + bk.bq) / 64    (f32)
//   value = codebook @ Wv^T + bv  (fp32-accurate via hi/lo split bf16 MFMA)
//   quant_out[n][c][s] = value[code0[n][s]][c]
//   negLogP[n] = sum_s ( log(sum_k exp(logit)) - logit[code,s] )
//
// R8 = R6 (113.0us, best) with ONE LINE changed in kC's block decode:
//      wg = n*1024 + st*32 + kt   (st OUTER, kt INNER; was kt outer)
//      Per-XCD working set becomes KWQ 2MB (re-touched every block, stays
//      L2-resident) + 2 LT panels (128KB, each fetched once) instead of the
//      full 2MB LT_n being cycled against 256MB of write-allocate traffic.
//      Tests the operand-re-read/L2-thrash theory (~512MB hidden reads).
// ---------------------------------------------------------------------------

typedef __attribute__((ext_vector_type(8))) short short8;
typedef __attribute__((ext_vector_type(4))) float f32x4;

__device__ __forceinline__ unsigned short f2bf(float f) {
  unsigned u = __float_as_uint(f);
  u += 0x7fffu + ((u >> 16) & 1u);
  return (unsigned short)(u >> 16);
}
__device__ __forceinline__ float bf2f(unsigned short h) {
  return __uint_as_float(((unsigned)h) << 16);
}
__device__ __forceinline__ void gl_lds16(const void* g, void* l) {
  __builtin_amdgcn_global_load_lds(
      (const __attribute__((address_space(1))) unsigned int*)g,
      (__attribute__((address_space(3))) unsigned int*)l, 16, 0, 0);
}

// ---------------------------------------------------------------------------
// kA: blocks 0..1023  : transpose+convert latent (n,c,s) f32 -> LT (n,s,c) bf16
//                       64x64 tiles: reads 256B bursts, writes 128B bursts.
//     blocks 1024..1279 (c'): WKQT[c'][c''] = sum_c Wk[c][c'']*Wq[c][c']; bkq
//     block 1280      : wkb[c''] = sum_c Wk[c][c'']*bq[c];  bkb = bk.bq
// ---------------------------------------------------------------------------
__global__ __launch_bounds__(256) void ka_trans_pre(
    const float* __restrict__ latent, unsigned short* __restrict__ lt,
    const float* __restrict__ Wq, const float* __restrict__ bq,
    const float* __restrict__ Wk, const float* __restrict__ bk,
    float* __restrict__ WKQT, float* __restrict__ bkq,
    float* __restrict__ wkb, float* __restrict__ bkb) {
  __shared__ __align__(16) float sm[64 * 65];  // 16.6 KB
  const int bid = blockIdx.x, t = threadIdx.x;
  if (bid < 1024) {
    float(*tile)[65] = (float(*)[65])sm;
    const int n = bid >> 8, ct = (bid >> 6) & 3, st = bid & 63;
    const float* src = latent + ((size_t)(n * 256 + ct * 64)) * 4096 + st * 64;
    // read: 1024 chunks of 16B; 16 chunks (256B) per c-row
#pragma unroll
    for (int i = 0; i < 4; ++i) {
      int chunk = i * 256 + t;
      int crow = chunk >> 4, sc = chunk & 15;
      f32x4 v = *(const f32x4*)(src + (size_t)crow * 4096 + sc * 4);
      tile[crow][sc * 4 + 0] = v[0];
      tile[crow][sc * 4 + 1] = v[1];
      tile[crow][sc * 4 + 2] = v[2];
      tile[crow][sc * 4 + 3] = v[3];
    }
    __syncthreads();
    // write: 512 chunks of 16B (8 bf16); 8 chunks (128B) per s-row
    unsigned short* dstb = lt + ((size_t)(n * 4096 + st * 64)) * 256 + ct * 64;
#pragma unroll
    for (int i = 0; i < 2; ++i) {
      int chunk = i * 256 + t;
      int srow = chunk >> 3, cc = chunk & 7;
      short8 h;
#pragma unroll
      for (int j = 0; j < 8; ++j) h[j] = (short)f2bf(tile[cc * 8 + j][srow]);
      *(short8*)(dstb + (size_t)srow * 256 + cc * 8) = h;
    }
    return;
  }
  float* red = sm;
  const int idx = bid - 1024;
  if (idx < 256) {
    const int c1 = idx;
    float acc = 0.f;
    for (int c = 0; c < 256; ++c) acc += Wk[c * 256 + t] * Wq[c * 256 + c1];
    WKQT[c1 * 256 + t] = acc;
    float v = bk[t] * Wq[t * 256 + c1];
#pragma unroll
    for (int m = 32; m >= 1; m >>= 1) v += __shfl_xor(v, m);
    if ((t & 63) == 0) red[t >> 6] = v;
    __syncthreads();
    if (t == 0) bkq[c1] = red[0] + red[1] + red[2] + red[3];
  } else {
    float acc = 0.f;
    for (int c = 0; c < 256; ++c) acc += Wk[c * 256 + t] * bq[c];
    wkb[t] = acc;
    float v = bk[t] * bq[t];
#pragma unroll
    for (int m = 32; m >= 1; m >>= 1) v += __shfl_xor(v, m);
    if ((t & 63) == 0) red[t >> 6] = v;
    __syncthreads();
    if (t == 0) bkb[0] = red[0] + red[1] + red[2] + red[3];
  }
}

// ---------------------------------------------------------------------------
// gemm_body: out[k][c] = (A[k][:] . Bt[c][:] + bias[c])*scale
//   A: 4096x256 f32, Bt: 256x256 f32, K=256. hi/lo bf16 split, 3-term MFMA.
//   BM=128, BN=64, BK=64; 256 threads (4 waves 2x2).
// ---------------------------------------------------------------------------
template <bool OUT_BF16>
__device__ __forceinline__ void gemm_body(char* smem, const float* __restrict__ A,
                                          const float* __restrict__ Bt,
                                          const float* __restrict__ bias,
                                          void* __restrict__ outv, float scale,
                                          int bm, int bn, int t) {
  // LDS: Ah 16K @0, Al 16K @16384, Bh 8K @32768, Bl 8K @40960
  const int lane = t & 63, wave = t >> 6;
  const int wr = wave >> 1, wc = wave & 1;
  const int l15 = lane & 15, lg = lane >> 4;
  f32x4 acc[4][2] = {};

  for (int kk = 0; kk < 4; ++kk) {
    if (kk) __syncthreads();
#pragma unroll
    for (int i = 0; i < 4; ++i) {
      int p = i * 256 + t;
      int row = p >> 3, cg = p & 7;
      const float* src = A + (bm * 128 + row) * 256 + kk * 64 + cg * 8;
      short8 hi, lo;
#pragma unroll
      for (int j = 0; j < 8; ++j) {
        float x = src[j];
        unsigned short h = f2bf(x);
        hi[j] = (short)h;
        lo[j] = (short)f2bf(x - bf2f(h));
      }
      int dst = (row * 64 + ((cg ^ (row & 7)) * 8)) * 2;
      *(short8*)(smem + dst) = hi;
      *(short8*)(smem + 16384 + dst) = lo;
    }
#pragma unroll
    for (int i = 0; i < 2; ++i) {
      int p = i * 256 + t;
      int row = p >> 3, cg = p & 7;
      const float* src = Bt + (bn * 64 + row) * 256 + kk * 64 + cg * 8;
      short8 hi, lo;
#pragma unroll
      for (int j = 0; j < 8; ++j) {
        float x = src[j];
        unsigned short h = f2bf(x);
        hi[j] = (short)h;
        lo[j] = (short)f2bf(x - bf2f(h));
      }
      int dst = (row * 64 + ((cg ^ (row & 7)) * 8)) * 2;
      *(short8*)(smem + 32768 + dst) = hi;
      *(short8*)(smem + 40960 + dst) = lo;
    }
    __syncthreads();
#pragma unroll
    for (int kk2 = 0; kk2 < 2; ++kk2) {
      short8 ah[4], al[4], bh[2], bl[2];
#pragma unroll
      for (int mi = 0; mi < 4; ++mi) {
        int ra = wr * 64 + mi * 16 + l15;
        int ca = (kk2 * 4 + lg) ^ (ra & 7);
        ah[mi] = *(const short8*)(smem + ra * 128 + ca * 16);
        al[mi] = *(const short8*)(smem + 16384 + ra * 128 + ca * 16);
      }
#pragma unroll
      for (int ni = 0; ni < 2; ++ni) {
        int rb = wc * 32 + ni * 16 + l15;
        int cb = (kk2 * 4 + lg) ^ (rb & 7);
        bh[ni] = *(const short8*)(smem + 32768 + rb * 128 + cb * 16);
        bl[ni] = *(const short8*)(smem + 40960 + rb * 128 + cb * 16);
      }
#pragma unroll
      for (int mi = 0; mi < 4; ++mi)
#pragma unroll
        for (int ni = 0; ni < 2; ++ni) {
          acc[mi][ni] = __builtin_amdgcn_mfma_f32_16x16x32_bf16(ah[mi], bh[ni], acc[mi][ni], 0, 0, 0);
          acc[mi][ni] = __builtin_amdgcn_mfma_f32_16x16x32_bf16(ah[mi], bl[ni], acc[mi][ni], 0, 0, 0);
          acc[mi][ni] = __builtin_amdgcn_mfma_f32_16x16x32_bf16(al[mi], bh[ni], acc[mi][ni], 0, 0, 0);
        }
    }
  }
#pragma unroll
  for (int mi = 0; mi < 4; ++mi) {
    int gk = bm * 128 + wr * 64 + mi * 16 + lg * 4;
#pragma unroll
    for (int ni = 0; ni < 2; ++ni) {
      int gc = bn * 64 + wc * 32 + ni * 16 + l15;
      float bv_ = bias[gc];
#pragma unroll
      for (int e = 0; e < 4; ++e) {
        float v = (acc[mi][ni][e] + bv_) * scale;
        int idx = (gk + e) * 256 + gc;
        if (OUT_BF16)
          ((unsigned short*)outv)[idx] = f2bf(v);
        else
          ((float*)outv)[idx] = v;
      }
    }
  }
}

// ---------------------------------------------------------------------------
// kB: blocks 0..127   -> VALUE = cb@Wv^T + bv (f32)
//     blocks 128..255 -> KWQ  = (cb@WKQT^T + BKQ)/64 (bf16)
//     blocks 256..767 -> KB[k] = (cb[k].wkb + bkb)/64, 8 rows/block
// ---------------------------------------------------------------------------
__global__ __launch_bounds__(256) void kb_weights(
    const float* __restrict__ cb, const float* __restrict__ Wv,
    const float* __restrict__ bv, float* __restrict__ VALUE,
    const float* __restrict__ WKQT, const float* __restrict__ BKQ,
    unsigned short* __restrict__ KWQ, const float* __restrict__ WKB,
    const float* __restrict__ BKB, float* __restrict__ KB) {
  __shared__ __align__(16) char smem[49152];
  const int bid = blockIdx.x, t = threadIdx.x;
  if (bid < 128) {
    gemm_body<false>(smem, cb, Wv, bv, (void*)VALUE, 1.0f, bid >> 2, bid & 3, t);
  } else if (bid < 256) {
    int b = bid - 128;
    gemm_body<true>(smem, cb, WKQT, BKQ, (void*)KWQ, 0.015625f, b >> 2, b & 3, t);
  } else {
    const int l32 = t & 31, r = t >> 5;
    const int row = (bid - 256) * 8 + r;
    float acc = 0.f;
#pragma unroll
    for (int j = 0; j < 8; ++j) {
      int c = l32 + j * 32;
      acc += cb[row * 256 + c] * WKB[c];
    }
#pragma unroll
    for (int m = 16; m >= 1; m >>= 1) acc += __shfl_xor(acc, m);
    if (l32 == 0) KB[row] = (acc + BKB[0]) * 0.015625f;
  }
}

// ---------------------------------------------------------------------------
// kC: blocks 0..511    -> quant gather: LDS-tiled transpose of value rows
//     blocks 512..4607 -> logit GEMM (m97 structure) + exp column partials
// ---------------------------------------------------------------------------
__global__ __launch_bounds__(256) void kc_logit_gather(
    const unsigned short* __restrict__ kwq, const unsigned short* __restrict__ lt,
    const float* __restrict__ kb, float* __restrict__ logit_out,
    float* __restrict__ part, const int* __restrict__ code,
    const float* __restrict__ value, float* __restrict__ outq) {
  __shared__ __align__(16) char smem[34816];
  const int bid0 = blockIdx.x, t = threadIdx.x;
  const int lane = t & 63, wave = t >> 6;

  if (bid0 < 512) {
    // ---- quant gather: 32 tokens/block, transpose via padded LDS ----
    float* vt = (float*)smem;            // [32][257]
    int* codes = (int*)(smem + 32896);   // 32 ints
    const int n = bid0 >> 7, s0 = (bid0 & 127) * 32;
    if (t < 32) codes[t] = code[(n << 12) + s0 + t];
    __syncthreads();
#pragma unroll
    for (int j = 0; j < 8; ++j) {
      int jj = wave * 8 + j;
      int idx = codes[jj];
      f32x4 v = *(const f32x4*)(value + (size_t)idx * 256 + lane * 4);
      float* d = vt + jj * 257 + lane * 4;
      d[0] = v[0]; d[1] = v[1]; d[2] = v[2]; d[3] = v[3];
    }
    __syncthreads();
    const int sl = t & 31, cg = t >> 5;  // cg 0..7
#pragma unroll
    for (int ci = 0; ci < 32; ++ci) {
      int c = ci * 8 + cg;
      __builtin_nontemporal_store(vt[sl * 257 + c],
                                  outq + (((size_t)(n * 256 + c)) << 12) + s0 + sl);
    }
    return;
  }

  // ---- logit GEMM ----
  const int bid = bid0 - 512;
  const int xcd = bid & 7, idx = bid >> 3;
  const int wg = xcd * 512 + idx;
  // R8: st OUTER, kt INNER (was n*1024 + kt*32 + st).  Per-XCD working set:
  // KWQ 2MB re-touched every block (L2-resident) + ~2 LT panels (128KB).
  const int n = wg >> 10, rr = wg & 1023, st = rr >> 5, kt = rr & 31;
  const int wr = wave >> 1, wc = wave & 1, l15 = lane & 15, lg = lane >> 4;
  f32x4 acc[4][4] = {};
  const unsigned short* abase = kwq + (size_t)kt * 128 * 256;
  const unsigned short* bbase = lt + ((size_t)n * 4096 + st * 128) * 256;

  auto stage = [&](int kk) {
#pragma unroll
    for (int i = 0; i < 4; ++i) {
      int p0 = (i * 4 + wave) * 64;
      int p = p0 + lane;
      int row = p >> 3, cl = p & 7;
      int goff = row * 256 + kk * 64 + ((cl ^ (row & 7)) * 8);
      gl_lds16(abase + goff, smem + p0 * 16);
      gl_lds16(bbase + goff, smem + 16384 + p0 * 16);
    }
  };

  stage(0);
  for (int kk = 0; kk < 4; ++kk) {
    __syncthreads();  // drains vmcnt -> tile kk visible
#pragma unroll
    for (int kk2 = 0; kk2 < 2; ++kk2) {
      short8 af[4], bfr[4];
#pragma unroll
      for (int mi = 0; mi < 4; ++mi) {
        int ra = wr * 64 + mi * 16 + l15;
        int ca = (kk2 * 4 + lg) ^ (ra & 7);
        af[mi] = *(const short8*)(smem + ra * 128 + ca * 16);
      }
#pragma unroll
      for (int ni = 0; ni < 4; ++ni) {
        int rb = wc * 64 + ni * 16 + l15;
        int cb = (kk2 * 4 + lg) ^ (rb & 7);
        bfr[ni] = *(const short8*)(smem + 16384 + rb * 128 + cb * 16);
      }
#pragma unroll
      for (int mi = 0; mi < 4; ++mi)
#pragma unroll
        for (int ni = 0; ni < 4; ++ni)
          acc[mi][ni] = __builtin_amdgcn_mfma_f32_16x16x32_bf16(af[mi], bfr[ni], acc[mi][ni], 0, 0, 0);
    }
    if (kk < 3) {
      __syncthreads();
      stage(kk + 1);
    }
  }

  // epilogue: add kb, write logits (nontemporal), accumulate exp column sums
  float colsum[4] = {0.f, 0.f, 0.f, 0.f};
  float* lbase = logit_out + (size_t)(n * 4096 + kt * 128) * 4096 + st * 128;
#pragma unroll
  for (int mi = 0; mi < 4; ++mi) {
    int rk = wr * 64 + mi * 16 + lg * 4;
    f32x4 kbv = *(const f32x4*)(kb + kt * 128 + rk);
#pragma unroll
    for (int ni = 0; ni < 4; ++ni) {
      int cs = wc * 64 + ni * 16 + l15;
      float* op = lbase + (size_t)rk * 4096 + cs;
#pragma unroll
      for (int e = 0; e < 4; ++e) {
        float v = acc[mi][ni][e] + kbv[e];
        __builtin_nontemporal_store(v, op + (size_t)e * 4096);
        colsum[ni] += __expf(v);
      }
    }
  }
#pragma unroll
  for (int ni = 0; ni < 4; ++ni) {
    colsum[ni] += __shfl_xor(colsum[ni], 16);
    colsum[ni] += __shfl_xor(colsum[ni], 32);
  }
  float* sums = (float*)(smem + 32768);  // [2][128]
  if (lane < 16) {
#pragma unroll
    for (int ni = 0; ni < 4; ++ni)
      sums[wr * 128 + wc * 64 + ni * 16 + lane] = colsum[ni];
  }
  __syncthreads();
  if (t < 128) {
    float tot = sums[t] + sums[128 + t];
    part[((size_t)(n * 32 + kt) << 12) + st * 128 + t] = tot;
  }
}

// ---------------------------------------------------------------------------
// kD: 64 blocks (n, 256-token chunk): partial negLogP (double) per block
// ---------------------------------------------------------------------------
__global__ __launch_bounds__(256) void kd_nlp(const float* __restrict__ part,
                                              const float* __restrict__ logit,
                                              const int* __restrict__ code,
                                              double* __restrict__ part2) {
  const int bid = blockIdx.x, t = threadIdx.x;
  const int n = bid >> 4;
  const int s = ((bid & 15) << 8) + t;
  float se = 0.f;
#pragma unroll
  for (int kt = 0; kt < 32; ++kt) se += part[((size_t)(n * 32 + kt) << 12) + s];
  int cc = code[(n << 12) + s];
  float lc = logit[((size_t)(n * 4096 + cc) << 12) + s];
  double a = (double)logf(se) - (double)lc;
#pragma unroll
  for (int m = 32; m >= 1; m >>= 1) a += __shfl_xor(a, m);
  __shared__ double red[4];
  if ((t & 63) == 0) red[t >> 6] = a;
  __syncthreads();
  if (t == 0) part2[bid] = red[0] + red[1] + red[2] + red[3];
}

// ---------------------------------------------------------------------------
// kE: final reduce, 1 block of 64: outn[n] = sum of 16 partials
// ---------------------------------------------------------------------------
__global__ __launch_bounds__(64) void ke_final(const double* __restrict__ part2,
                                               float* __restrict__ outn) {
  const int t = threadIdx.x;
  const int n = t >> 4, i = t & 15;
  double v = part2[n * 16 + i];
#pragma unroll
  for (int m = 8; m >= 1; m >>= 1) v += __shfl_xor(v, m);
  if (i == 0) outn[n] = (float)v;
}

// ---------------------------------------------------------------------------
extern "C" void kernel_launch(void* const* d_in, const int* in_sizes, int n_in,
                              void* d_out, int out_size, void* d_ws, size_t ws_size,
                              hipStream_t stream) {
  const float* latent = (const float*)d_in[0];
  const int* code = (const int*)d_in[1];
  const float* cb = (const float*)d_in[2];
  const float* Wq = (const float*)d_in[3];
  const float* bq = (const float*)d_in[4];
  const float* Wk = (const float*)d_in[5];
  const float* bk = (const float*)d_in[6];
  const float* Wv = (const float*)d_in[7];
  const float* bv = (const float*)d_in[8];

  float* out = (float*)d_out;
  float* outq = out;                // 4*256*4096
  float* outl = out + 4194304;      // 4*4096*4096
  float* outn = out + 71303168;     // 4

  char* ws = (char*)d_ws;
  unsigned short* LT = (unsigned short*)(ws + 0);         // 8 MB  bf16 (n,s,c)
  unsigned short* KWQ = (unsigned short*)(ws + 8388608);  // 2 MB  bf16 (k,c)
  float* KB = (float*)(ws + 10485760);                    // 16 KB
  float* VALUE = (float*)(ws + 10502144);                 // 4 MB  f32 (k,c)
  float* PART = (float*)(ws + 14696448);                  // 2 MB  f32 (n,32,s)
  float* WKQT = (float*)(ws + 16793600);                  // 256 KB
  float* BKQ = (float*)(ws + 17055744);                   // 1 KB
  float* WKB = (float*)(ws + 17056768);                   // 1 KB
  float* BKB = (float*)(ws + 17057792);                   // 4 B
  double* PART2 = (double*)(ws + 17058816);               // 512 B

  ka_trans_pre<<<1281, 256, 0, stream>>>(latent, LT, Wq, bq, Wk, bk, WKQT, BKQ, WKB, BKB);
  kb_weights<<<768, 256, 0, stream>>>(cb, Wv, bv, VALUE, WKQT, BKQ, KWQ, WKB, BKB, KB);
  kc_logit_gather<<<4608, 256, 0, stream>>>(KWQ, LT, KB, outl, PART, code, VALUE, outq);
  kd_nlp<<<64, 256, 0, stream>>>(PART, outl, code, PART2);
  ke_final<<<1, 64, 0, stream>>>(PART2, outn);
}

// Round 9
// 103.115 us; speedup vs baseline: 1.3077x; 1.3077x over previous
//
#include <hip/hip_runtime.h>

// ---------------------------------------------------------------------------
// TransformerQuantizerRein on MI355X (gfx950)
// N=4, C=256, H=W=64 (S=4096 tokens), K=4096 codes.
//
//   logit[n][k][s] = sum_c' kWq[k][c'] * latent[n][c'][s] + kb[k]
//     kWq = (codebook @ (Wk^T @ Wq) + bk@Wq) / 64  (bf16, prescaled)
//     kb  = (codebook @ (Wk^T bq) + bk.bq) / 64    (f32)
//   value = codebook @ Wv^T + bv  (fp32-accurate via hi/lo split bf16 MFMA)
//   quant_out[n][c][s] = value[code0[n][s]][c]
//   negLogP[n] = sum_s ( log(sum_k exp(logit)) - logit[code,s] )
//
// R9 = R6 (113.0us best; kt-outer/st-inner write order PROVEN by R8's -22us
//      regression) with ONE change: kC logit GEMM uses 32x32x16 MFMA.
//      C/D layout col=lane&31 -> each store inst covers 2 FULL 128B lines
//      (vs 4x 64B half-lines with 16x16x32), no extra barriers/serialization
//      (R7's failure mode). Also higher MFMA rate (2382 vs 2075 TF ubench)
//      and 1 colsum shuffle instead of 2.
// ---------------------------------------------------------------------------

typedef __attribute__((ext_vector_type(8))) short short8;
typedef __attribute__((ext_vector_type(4))) float f32x4;
typedef __attribute__((ext_vector_type(16))) float f32x16;

__device__ __forceinline__ unsigned short f2bf(float f) {
  unsigned u = __float_as_uint(f);
  u += 0x7fffu + ((u >> 16) & 1u);
  return (unsigned short)(u >> 16);
}
__device__ __forceinline__ float bf2f(unsigned short h) {
  return __uint_as_float(((unsigned)h) << 16);
}
__device__ __forceinline__ void gl_lds16(const void* g, void* l) {
  __builtin_amdgcn_global_load_lds(
      (const __attribute__((address_space(1))) unsigned int*)g,
      (__attribute__((address_space(3))) unsigned int*)l, 16, 0, 0);
}

// ---------------------------------------------------------------------------
// kA: blocks 0..1023  : transpose+convert latent (n,c,s) f32 -> LT (n,s,c) bf16
//                       64x64 tiles: reads 256B bursts, writes 128B bursts.
//     blocks 1024..1279 (c'): WKQT[c'][c''] = sum_c Wk[c][c'']*Wq[c][c']; bkq
//     block 1280      : wkb[c''] = sum_c Wk[c][c'']*bq[c];  bkb = bk.bq
// ---------------------------------------------------------------------------
__global__ __launch_bounds__(256) void ka_trans_pre(
    const float* __restrict__ latent, unsigned short* __restrict__ lt,
    const float* __restrict__ Wq, const float* __restrict__ bq,
    const float* __restrict__ Wk, const float* __restrict__ bk,
    float* __restrict__ WKQT, float* __restrict__ bkq,
    float* __restrict__ wkb, float* __restrict__ bkb) {
  __shared__ __align__(16) float sm[64 * 65];  // 16.6 KB
  const int bid = blockIdx.x, t = threadIdx.x;
  if (bid < 1024) {
    float(*tile)[65] = (float(*)[65])sm;
    const int n = bid >> 8, ct = (bid >> 6) & 3, st = bid & 63;
    const float* src = latent + ((size_t)(n * 256 + ct * 64)) * 4096 + st * 64;
    // read: 1024 chunks of 16B; 16 chunks (256B) per c-row
#pragma unroll
    for (int i = 0; i < 4; ++i) {
      int chunk = i * 256 + t;
      int crow = chunk >> 4, sc = chunk & 15;
      f32x4 v = *(const f32x4*)(src + (size_t)crow * 4096 + sc * 4);
      tile[crow][sc * 4 + 0] = v[0];
      tile[crow][sc * 4 + 1] = v[1];
      tile[crow][sc * 4 + 2] = v[2];
      tile[crow][sc * 4 + 3] = v[3];
    }
    __syncthreads();
    // write: 512 chunks of 16B (8 bf16); 8 chunks (128B) per s-row
    unsigned short* dstb = lt + ((size_t)(n * 4096 + st * 64)) * 256 + ct * 64;
#pragma unroll
    for (int i = 0; i < 2; ++i) {
      int chunk = i * 256 + t;
      int srow = chunk >> 3, cc = chunk & 7;
      short8 h;
#pragma unroll
      for (int j = 0; j < 8; ++j) h[j] = (short)f2bf(tile[cc * 8 + j][srow]);
      *(short8*)(dstb + (size_t)srow * 256 + cc * 8) = h;
    }
    return;
  }
  float* red = sm;
  const int idx = bid - 1024;
  if (idx < 256) {
    const int c1 = idx;
    float acc = 0.f;
    for (int c = 0; c < 256; ++c) acc += Wk[c * 256 + t] * Wq[c * 256 + c1];
    WKQT[c1 * 256 + t] = acc;
    float v = bk[t] * Wq[t * 256 + c1];
#pragma unroll
    for (int m = 32; m >= 1; m >>= 1) v += __shfl_xor(v, m);
    if ((t & 63) == 0) red[t >> 6] = v;
    __syncthreads();
    if (t == 0) bkq[c1] = red[0] + red[1] + red[2] + red[3];
  } else {
    float acc = 0.f;
    for (int c = 0; c < 256; ++c) acc += Wk[c * 256 + t] * bq[c];
    wkb[t] = acc;
    float v = bk[t] * bq[t];
#pragma unroll
    for (int m = 32; m >= 1; m >>= 1) v += __shfl_xor(v, m);
    if ((t & 63) == 0) red[t >> 6] = v;
    __syncthreads();
    if (t == 0) bkb[0] = red[0] + red[1] + red[2] + red[3];
  }
}

// ---------------------------------------------------------------------------
// gemm_body: out[k][c] = (A[k][:] . Bt[c][:] + bias[c])*scale
//   A: 4096x256 f32, Bt: 256x256 f32, K=256. hi/lo bf16 split, 3-term MFMA.
//   BM=128, BN=64, BK=64; 256 threads (4 waves 2x2).
// ---------------------------------------------------------------------------
template <bool OUT_BF16>
__device__ __forceinline__ void gemm_body(char* smem, const float* __restrict__ A,
                                          const float* __restrict__ Bt,
                                          const float* __restrict__ bias,
                                          void* __restrict__ outv, float scale,
                                          int bm, int bn, int t) {
  // LDS: Ah 16K @0, Al 16K @16384, Bh 8K @32768, Bl 8K @40960
  const int lane = t & 63, wave = t >> 6;
  const int wr = wave >> 1, wc = wave & 1;
  const int l15 = lane & 15, lg = lane >> 4;
  f32x4 acc[4][2] = {};

  for (int kk = 0; kk < 4; ++kk) {
    if (kk) __syncthreads();
#pragma unroll
    for (int i = 0; i < 4; ++i) {
      int p = i * 256 + t;
      int row = p >> 3, cg = p & 7;
      const float* src = A + (bm * 128 + row) * 256 + kk * 64 + cg * 8;
      short8 hi, lo;
#pragma unroll
      for (int j = 0; j < 8; ++j) {
        float x = src[j];
        unsigned short h = f2bf(x);
        hi[j] = (short)h;
        lo[j] = (short)f2bf(x - bf2f(h));
      }
      int dst = (row * 64 + ((cg ^ (row & 7)) * 8)) * 2;
      *(short8*)(smem + dst) = hi;
      *(short8*)(smem + 16384 + dst) = lo;
    }
#pragma unroll
    for (int i = 0; i < 2; ++i) {
      int p = i * 256 + t;
      int row = p >> 3, cg = p & 7;
      const float* src = Bt + (bn * 64 + row) * 256 + kk * 64 + cg * 8;
      short8 hi, lo;
#pragma unroll
      for (int j = 0; j < 8; ++j) {
        float x = src[j];
        unsigned short h = f2bf(x);
        hi[j] = (short)h;
        lo[j] = (short)f2bf(x - bf2f(h));
      }
      int dst = (row * 64 + ((cg ^ (row & 7)) * 8)) * 2;
      *(short8*)(smem + 32768 + dst) = hi;
      *(short8*)(smem + 40960 + dst) = lo;
    }
    __syncthreads();
#pragma unroll
    for (int kk2 = 0; kk2 < 2; ++kk2) {
      short8 ah[4], al[4], bh[2], bl[2];
#pragma unroll
      for (int mi = 0; mi < 4; ++mi) {
        int ra = wr * 64 + mi * 16 + l15;
        int ca = (kk2 * 4 + lg) ^ (ra & 7);
        ah[mi] = *(const short8*)(smem + ra * 128 + ca * 16);
        al[mi] = *(const short8*)(smem + 16384 + ra * 128 + ca * 16);
      }
#pragma unroll
      for (int ni = 0; ni < 2; ++ni) {
        int rb = wc * 32 + ni * 16 + l15;
        int cb = (kk2 * 4 + lg) ^ (rb & 7);
        bh[ni] = *(const short8*)(smem + 32768 + rb * 128 + cb * 16);
        bl[ni] = *(const short8*)(smem + 40960 + rb * 128 + cb * 16);
      }
#pragma unroll
      for (int mi = 0; mi < 4; ++mi)
#pragma unroll
        for (int ni = 0; ni < 2; ++ni) {
          acc[mi][ni] = __builtin_amdgcn_mfma_f32_16x16x32_bf16(ah[mi], bh[ni], acc[mi][ni], 0, 0, 0);
          acc[mi][ni] = __builtin_amdgcn_mfma_f32_16x16x32_bf16(ah[mi], bl[ni], acc[mi][ni], 0, 0, 0);
          acc[mi][ni] = __builtin_amdgcn_mfma_f32_16x16x32_bf16(al[mi], bh[ni], acc[mi][ni], 0, 0, 0);
        }
    }
  }
#pragma unroll
  for (int mi = 0; mi < 4; ++mi) {
    int gk = bm * 128 + wr * 64 + mi * 16 + lg * 4;
#pragma unroll
    for (int ni = 0; ni < 2; ++ni) {
      int gc = bn * 64 + wc * 32 + ni * 16 + l15;
      float bv_ = bias[gc];
#pragma unroll
      for (int e = 0; e < 4; ++e) {
        float v = (acc[mi][ni][e] + bv_) * scale;
        int idx = (gk + e) * 256 + gc;
        if (OUT_BF16)
          ((unsigned short*)outv)[idx] = f2bf(v);
        else
          ((float*)outv)[idx] = v;
      }
    }
  }
}

// ---------------------------------------------------------------------------
// kB: blocks 0..127   -> VALUE = cb@Wv^T + bv (f32)
//     blocks 128..255 -> KWQ  = (cb@WKQT^T + BKQ)/64 (bf16)
//     blocks 256..767 -> KB[k] = (cb[k].wkb + bkb)/64, 8 rows/block
// ---------------------------------------------------------------------------
__global__ __launch_bounds__(256) void kb_weights(
    const float* __restrict__ cb, const float* __restrict__ Wv,
    const float* __restrict__ bv, float* __restrict__ VALUE,
    const float* __restrict__ WKQT, const float* __restrict__ BKQ,
    unsigned short* __restrict__ KWQ, const float* __restrict__ WKB,
    const float* __restrict__ BKB, float* __restrict__ KB) {
  __shared__ __align__(16) char smem[49152];
  const int bid = blockIdx.x, t = threadIdx.x;
  if (bid < 128) {
    gemm_body<false>(smem, cb, Wv, bv, (void*)VALUE, 1.0f, bid >> 2, bid & 3, t);
  } else if (bid < 256) {
    int b = bid - 128;
    gemm_body<true>(smem, cb, WKQT, BKQ, (void*)KWQ, 0.015625f, b >> 2, b & 3, t);
  } else {
    const int l32 = t & 31, r = t >> 5;
    const int row = (bid - 256) * 8 + r;
    float acc = 0.f;
#pragma unroll
    for (int j = 0; j < 8; ++j) {
      int c = l32 + j * 32;
      acc += cb[row * 256 + c] * WKB[c];
    }
#pragma unroll
    for (int m = 16; m >= 1; m >>= 1) acc += __shfl_xor(acc, m);
    if (l32 == 0) KB[row] = (acc + BKB[0]) * 0.015625f;
  }
}

// ---------------------------------------------------------------------------
// kC: blocks 0..511    -> quant gather: LDS-tiled transpose of value rows
//     blocks 512..4607 -> logit GEMM, 32x32x16 MFMA (full-line stores)
// ---------------------------------------------------------------------------
__global__ __launch_bounds__(256) void kc_logit_gather(
    const unsigned short* __restrict__ kwq, const unsigned short* __restrict__ lt,
    const float* __restrict__ kb, float* __restrict__ logit_out,
    float* __restrict__ part, const int* __restrict__ code,
    const float* __restrict__ value, float* __restrict__ outq) {
  __shared__ __align__(16) char smem[34816];
  const int bid0 = blockIdx.x, t = threadIdx.x;
  const int lane = t & 63, wave = t >> 6;

  if (bid0 < 512) {
    // ---- quant gather: 32 tokens/block, transpose via padded LDS ----
    float* vt = (float*)smem;            // [32][257]
    int* codes = (int*)(smem + 32896);   // 32 ints
    const int n = bid0 >> 7, s0 = (bid0 & 127) * 32;
    if (t < 32) codes[t] = code[(n << 12) + s0 + t];
    __syncthreads();
#pragma unroll
    for (int j = 0; j < 8; ++j) {
      int jj = wave * 8 + j;
      int idx = codes[jj];
      f32x4 v = *(const f32x4*)(value + (size_t)idx * 256 + lane * 4);
      float* d = vt + jj * 257 + lane * 4;
      d[0] = v[0]; d[1] = v[1]; d[2] = v[2]; d[3] = v[3];
    }
    __syncthreads();
    const int sl = t & 31, cg = t >> 5;  // cg 0..7
#pragma unroll
    for (int ci = 0; ci < 32; ++ci) {
      int c = ci * 8 + cg;
      __builtin_nontemporal_store(vt[sl * 257 + c],
                                  outq + (((size_t)(n * 256 + c)) << 12) + s0 + sl);
    }
    return;
  }

  // ---- logit GEMM (32x32x16) ----
  const int bid = bid0 - 512;
  const int xcd = bid & 7, idx = bid >> 3;
  const int wg = xcd * 512 + idx;
  const int n = wg >> 10, rr = wg & 1023, kt = rr >> 5, st = rr & 31;  // R6 order
  const int wr = wave >> 1, wc = wave & 1;
  const int l31 = lane & 31, hi = lane >> 5;
  f32x16 acc[2][2] = {};
  const unsigned short* abase = kwq + (size_t)kt * 128 * 256;
  const unsigned short* bbase = lt + ((size_t)n * 4096 + st * 128) * 256;

  auto stage = [&](int kk) {
#pragma unroll
    for (int i = 0; i < 4; ++i) {
      int p0 = (i * 4 + wave) * 64;
      int p = p0 + lane;
      int row = p >> 3, cl = p & 7;
      int goff = row * 256 + kk * 64 + ((cl ^ (row & 7)) * 8);
      gl_lds16(abase + goff, smem + p0 * 16);
      gl_lds16(bbase + goff, smem + 16384 + p0 * 16);
    }
  };

  stage(0);
  for (int kk = 0; kk < 4; ++kk) {
    __syncthreads();  // drains vmcnt -> tile kk visible
#pragma unroll
    for (int kc = 0; kc < 4; ++kc) {  // K=16 chunks within the 64-K tile
      short8 af[2], bf[2];
      const int ch = kc * 2 + hi;     // 8-elem chunk index 0..7
#pragma unroll
      for (int mi = 0; mi < 2; ++mi) {
        int ra = wr * 64 + mi * 32 + l31;
        af[mi] = *(const short8*)(smem + ra * 128 + ((ch ^ (ra & 7)) * 16));
      }
#pragma unroll
      for (int ni = 0; ni < 2; ++ni) {
        int rb = wc * 64 + ni * 32 + l31;
        bf[ni] = *(const short8*)(smem + 16384 + rb * 128 + ((ch ^ (rb & 7)) * 16));
      }
#pragma unroll
      for (int mi = 0; mi < 2; ++mi)
#pragma unroll
        for (int ni = 0; ni < 2; ++ni)
          acc[mi][ni] = __builtin_amdgcn_mfma_f32_32x32x16_bf16(af[mi], bf[ni], acc[mi][ni], 0, 0, 0);
    }
    if (kk < 3) {
      __syncthreads();
      stage(kk + 1);
    }
  }

  // epilogue: D col = lane&31 (32 consecutive s), row = q*8 + (reg&3... ) via
  // verified mapping row = (reg&3) + 8*(reg>>2) + 4*hi. Each store inst:
  // 64 lanes cover 2 rows x 128B FULL lines.
  float colsum[2] = {0.f, 0.f};
  float* lbase = logit_out + (size_t)(n * 4096 + kt * 128) * 4096 + st * 128;
#pragma unroll
  for (int mi = 0; mi < 2; ++mi) {
#pragma unroll
    for (int ni = 0; ni < 2; ++ni) {
      int cs = wc * 64 + ni * 32 + l31;
#pragma unroll
      for (int q = 0; q < 4; ++q) {     // reg groups: rows r0..r0+3
        int r0 = wr * 64 + mi * 32 + q * 8 + hi * 4;
        f32x4 kbv = *(const f32x4*)(kb + kt * 128 + r0);
#pragma unroll
        for (int e = 0; e < 4; ++e) {
          float v = acc[mi][ni][q * 4 + e] + kbv[e];
          __builtin_nontemporal_store(v, lbase + (size_t)(r0 + e) * 4096 + cs);
          colsum[ni] += __expf(v);
        }
      }
    }
  }
  // col cs owned by lanes l and l+32 -> single xor-32 reduce
#pragma unroll
  for (int ni = 0; ni < 2; ++ni) colsum[ni] += __shfl_xor(colsum[ni], 32);
  float* sums = (float*)(smem + 32768);  // [2][128]
  if (lane < 32) {
#pragma unroll
    for (int ni = 0; ni < 2; ++ni)
      sums[wr * 128 + wc * 64 + ni * 32 + l31] = colsum[ni];
  }
  __syncthreads();
  if (t < 128) {
    float tot = sums[t] + sums[128 + t];
    part[((size_t)(n * 32 + kt) << 12) + st * 128 + t] = tot;
  }
}

// ---------------------------------------------------------------------------
// kD: 64 blocks (n, 256-token chunk): partial negLogP (double) per block
// ---------------------------------------------------------------------------
__global__ __launch_bounds__(256) void kd_nlp(const float* __restrict__ part,
                                              const float* __restrict__ logit,
                                              const int* __restrict__ code,
                                              double* __restrict__ part2) {
  const int bid = blockIdx.x, t = threadIdx.x;
  const int n = bid >> 4;
  const int s = ((bid & 15) << 8) + t;
  float se = 0.f;
#pragma unroll
  for (int kt = 0; kt < 32; ++kt) se += part[((size_t)(n * 32 + kt) << 12) + s];
  int cc = code[(n << 12) + s];
  float lc = logit[((size_t)(n * 4096 + cc) << 12) + s];
  double a = (double)logf(se) - (double)lc;
#pragma unroll
  for (int m = 32; m >= 1; m >>= 1) a += __shfl_xor(a, m);
  __shared__ double red[4];
  if ((t & 63) == 0) red[t >> 6] = a;
  __syncthreads();
  if (t == 0) part2[bid] = red[0] + red[1] + red[2] + red[3];
}

// ---------------------------------------------------------------------------
// kE: final reduce, 1 block of 64: outn[n] = sum of 16 partials
// ---------------------------------------------------------------------------
__global__ __launch_bounds__(64) void ke_final(const double* __restrict__ part2,
                                               float* __restrict__ outn) {
  const int t = threadIdx.x;
  const int n = t >> 4, i = t & 15;
  double v = part2[n * 16 + i];
#pragma unroll
  for (int m = 8; m >= 1; m >>= 1) v += __shfl_xor(v, m);
  if (i == 0) outn[n] = (float)v;
}

// ---------------------------------------------------------------------------
extern "C" void kernel_launch(void* const* d_in, const int* in_sizes, int n_in,
                              void* d_out, int out_size, void* d_ws, size_t ws_size,
                              hipStream_t stream) {
  const float* latent = (const float*)d_in[0];
  const int* code = (const int*)d_in[1];
  const float* cb = (const float*)d_in[2];
  const float* Wq = (const float*)d_in[3];
  const float* bq = (const float*)d_in[4];
  const float* Wk = (const float*)d_in[5];
  const float* bk = (const float*)d_in[6];
  const float* Wv = (const float*)d_in[7];
  const float* bv = (const float*)d_in[8];

  float* out = (float*)d_out;
  float* outq = out;                // 4*256*4096
  float* outl = out + 4194304;      // 4*4096*4096
  float* outn = out + 71303168;     // 4

  char* ws = (char*)d_ws;
  unsigned short* LT = (unsigned short*)(ws + 0);         // 8 MB  bf16 (n,s,c)
  unsigned short* KWQ = (unsigned short*)(ws + 8388608);  // 2 MB  bf16 (k,c)
  float* KB = (float*)(ws + 10485760);                    // 16 KB
  float* VALUE = (float*)(ws + 10502144);                 // 4 MB  f32 (k,c)
  float* PART = (float*)(ws + 14696448);                  // 2 MB  f32 (n,32,s)
  float* WKQT = (float*)(ws + 16793600);                  // 256 KB
  float* BKQ = (float*)(ws + 17055744);                   // 1 KB
  float* WKB = (float*)(ws + 17056768);                   // 1 KB
  float* BKB = (float*)(ws + 17057792);                   // 4 B
  double* PART2 = (double*)(ws + 17058816);               // 512 B

  ka_trans_pre<<<1281, 256, 0, stream>>>(latent, LT, Wq, bq, Wk, bk, WKQT, BKQ, WKB, BKB);
  kb_weights<<<768, 256, 0, stream>>>(cb, Wv, bv, VALUE, WKQT, BKQ, KWQ, WKB, BKB, KB);
  kc_logit_gather<<<4608, 256, 0, stream>>>(KWQ, LT, KB, outl, PART, code, VALUE, outq);
  kd_nlp<<<64, 256, 0, stream>>>(PART, outl, code, PART2);
  ke_final<<<1, 64, 0, stream>>>(PART2, outn);
}

// Round 10
// 97.097 us; speedup vs baseline: 1.3888x; 1.0620x over previous
//
#include <hip/hip_runtime.h>

// ---------------------------------------------------------------------------
// TransformerQuantizerRein on MI355X (gfx950)
// N=4, C=256, H=W=64 (S=4096 tokens), K=4096 codes.
//
//   logit[n][k][s] = sum_c' kWq[k][c'] * latent[n][c'][s] + kb[k]
//     kWq = (codebook @ (Wk^T @ Wq) + bk@Wq) / 64  (bf16, prescaled)
//     kb  = (codebook @ (Wk^T bq) + bk.bq) / 64    (f32)
//   value = codebook @ Wv^T + bv  (fp32-accurate via hi/lo split bf16 MFMA)
//   quant_out[n][c][s] = value[code0[n][s]][c]
//   negLogP[n] = sum_s ( log(sum_k exp(logit)) - logit[code,s] )
//
// R10 = R9 (103.1us best: 32x32x16 MFMA full-line stores, kt-outer order) +
//   (a) VALUE GEMM moved from kB into kA (overlaps transpose; R3/R4 proved
//       the 48KB-LDS kA costs ~0),
//   (b) kC epilogue loops reordered (mi,q,e,ni) so consecutive store insts
//       fill 256B per row (2 adjacent full 128B lines) - DRAM-sequential.
//       colsum accumulation order per ni unchanged -> bit-identical.
// ---------------------------------------------------------------------------

typedef __attribute__((ext_vector_type(8))) short short8;
typedef __attribute__((ext_vector_type(4))) float f32x4;
typedef __attribute__((ext_vector_type(16))) float f32x16;

__device__ __forceinline__ unsigned short f2bf(float f) {
  unsigned u = __float_as_uint(f);
  u += 0x7fffu + ((u >> 16) & 1u);
  return (unsigned short)(u >> 16);
}
__device__ __forceinline__ float bf2f(unsigned short h) {
  return __uint_as_float(((unsigned)h) << 16);
}
__device__ __forceinline__ void gl_lds16(const void* g, void* l) {
  __builtin_amdgcn_global_load_lds(
      (const __attribute__((address_space(1))) unsigned int*)g,
      (__attribute__((address_space(3))) unsigned int*)l, 16, 0, 0);
}

// ---------------------------------------------------------------------------
// gemm_body: out[k][c] = (A[k][:] . Bt[c][:] + bias[c])*scale
//   A: 4096x256 f32, Bt: 256x256 f32, K=256. hi/lo bf16 split, 3-term MFMA.
//   BM=128, BN=64, BK=64; 256 threads (4 waves 2x2).
// ---------------------------------------------------------------------------
template <bool OUT_BF16>
__device__ __forceinline__ void gemm_body(char* smem, const float* __restrict__ A,
                                          const float* __restrict__ Bt,
                                          const float* __restrict__ bias,
                                          void* __restrict__ outv, float scale,
                                          int bm, int bn, int t) {
  // LDS: Ah 16K @0, Al 16K @16384, Bh 8K @32768, Bl 8K @40960
  const int lane = t & 63, wave = t >> 6;
  const int wr = wave >> 1, wc = wave & 1;
  const int l15 = lane & 15, lg = lane >> 4;
  f32x4 acc[4][2] = {};

  for (int kk = 0; kk < 4; ++kk) {
    if (kk) __syncthreads();
#pragma unroll
    for (int i = 0; i < 4; ++i) {
      int p = i * 256 + t;
      int row = p >> 3, cg = p & 7;
      const float* src = A + (bm * 128 + row) * 256 + kk * 64 + cg * 8;
      short8 hi, lo;
#pragma unroll
      for (int j = 0; j < 8; ++j) {
        float x = src[j];
        unsigned short h = f2bf(x);
        hi[j] = (short)h;
        lo[j] = (short)f2bf(x - bf2f(h));
      }
      int dst = (row * 64 + ((cg ^ (row & 7)) * 8)) * 2;
      *(short8*)(smem + dst) = hi;
      *(short8*)(smem + 16384 + dst) = lo;
    }
#pragma unroll
    for (int i = 0; i < 2; ++i) {
      int p = i * 256 + t;
      int row = p >> 3, cg = p & 7;
      const float* src = Bt + (bn * 64 + row) * 256 + kk * 64 + cg * 8;
      short8 hi, lo;
#pragma unroll
      for (int j = 0; j < 8; ++j) {
        float x = src[j];
        unsigned short h = f2bf(x);
        hi[j] = (short)h;
        lo[j] = (short)f2bf(x - bf2f(h));
      }
      int dst = (row * 64 + ((cg ^ (row & 7)) * 8)) * 2;
      *(short8*)(smem + 32768 + dst) = hi;
      *(short8*)(smem + 40960 + dst) = lo;
    }
    __syncthreads();
#pragma unroll
    for (int kk2 = 0; kk2 < 2; ++kk2) {
      short8 ah[4], al[4], bh[2], bl[2];
#pragma unroll
      for (int mi = 0; mi < 4; ++mi) {
        int ra = wr * 64 + mi * 16 + l15;
        int ca = (kk2 * 4 + lg) ^ (ra & 7);
        ah[mi] = *(const short8*)(smem + ra * 128 + ca * 16);
        al[mi] = *(const short8*)(smem + 16384 + ra * 128 + ca * 16);
      }
#pragma unroll
      for (int ni = 0; ni < 2; ++ni) {
        int rb = wc * 32 + ni * 16 + l15;
        int cb = (kk2 * 4 + lg) ^ (rb & 7);
        bh[ni] = *(const short8*)(smem + 32768 + rb * 128 + cb * 16);
        bl[ni] = *(const short8*)(smem + 40960 + rb * 128 + cb * 16);
      }
#pragma unroll
      for (int mi = 0; mi < 4; ++mi)
#pragma unroll
        for (int ni = 0; ni < 2; ++ni) {
          acc[mi][ni] = __builtin_amdgcn_mfma_f32_16x16x32_bf16(ah[mi], bh[ni], acc[mi][ni], 0, 0, 0);
          acc[mi][ni] = __builtin_amdgcn_mfma_f32_16x16x32_bf16(ah[mi], bl[ni], acc[mi][ni], 0, 0, 0);
          acc[mi][ni] = __builtin_amdgcn_mfma_f32_16x16x32_bf16(al[mi], bh[ni], acc[mi][ni], 0, 0, 0);
        }
    }
  }
#pragma unroll
  for (int mi = 0; mi < 4; ++mi) {
    int gk = bm * 128 + wr * 64 + mi * 16 + lg * 4;
#pragma unroll
    for (int ni = 0; ni < 2; ++ni) {
      int gc = bn * 64 + wc * 32 + ni * 16 + l15;
      float bv_ = bias[gc];
#pragma unroll
      for (int e = 0; e < 4; ++e) {
        float v = (acc[mi][ni][e] + bv_) * scale;
        int idx = (gk + e) * 256 + gc;
        if (OUT_BF16)
          ((unsigned short*)outv)[idx] = f2bf(v);
        else
          ((float*)outv)[idx] = v;
      }
    }
  }
}

// ---------------------------------------------------------------------------
// kA: blocks 0..1023   : transpose latent (n,c,s) f32 -> LT (n,s,c) bf16, 64x64
//     blocks 1024..1151: VALUE = cb@Wv^T + bv (f32)   [independent, overlaps]
//     blocks 1152..1407: WKQT[c1][c''] = sum_c' Wk[c'][c'']*Wq[c'][c1]; bkq
//     block 1408       : wkb[c''] = sum_c Wk[c][c'']*bq[c];  bkb = bk.bq
// ---------------------------------------------------------------------------
__global__ __launch_bounds__(256) void ka_trans_pre(
    const float* __restrict__ latent, unsigned short* __restrict__ lt,
    const float* __restrict__ Wq, const float* __restrict__ bq,
    const float* __restrict__ Wk, const float* __restrict__ bk,
    float* __restrict__ WKQT, float* __restrict__ bkq,
    float* __restrict__ wkb, float* __restrict__ bkb,
    const float* __restrict__ cb, const float* __restrict__ Wv,
    const float* __restrict__ bv, float* __restrict__ VALUE) {
  __shared__ __align__(16) char smem[49152];
  const int bid = blockIdx.x, t = threadIdx.x;
  if (bid < 1024) {
    float(*tile)[65] = (float(*)[65])smem;  // 64x65 f32 = 16.6 KB
    const int n = bid >> 8, ct = (bid >> 6) & 3, st = bid & 63;
    const float* src = latent + ((size_t)(n * 256 + ct * 64)) * 4096 + st * 64;
#pragma unroll
    for (int i = 0; i < 4; ++i) {
      int chunk = i * 256 + t;
      int crow = chunk >> 4, sc = chunk & 15;
      f32x4 v = *(const f32x4*)(src + (size_t)crow * 4096 + sc * 4);
      tile[crow][sc * 4 + 0] = v[0];
      tile[crow][sc * 4 + 1] = v[1];
      tile[crow][sc * 4 + 2] = v[2];
      tile[crow][sc * 4 + 3] = v[3];
    }
    __syncthreads();
    unsigned short* dstb = lt + ((size_t)(n * 4096 + st * 64)) * 256 + ct * 64;
#pragma unroll
    for (int i = 0; i < 2; ++i) {
      int chunk = i * 256 + t;
      int srow = chunk >> 3, cc = chunk & 7;
      short8 h;
#pragma unroll
      for (int j = 0; j < 8; ++j) h[j] = (short)f2bf(tile[cc * 8 + j][srow]);
      *(short8*)(dstb + (size_t)srow * 256 + cc * 8) = h;
    }
    return;
  }
  if (bid < 1152) {
    int b = bid - 1024;
    gemm_body<false>(smem, cb, Wv, bv, (void*)VALUE, 1.0f, b >> 2, b & 3, t);
    return;
  }
  float* red = (float*)smem;
  if (bid < 1408) {
    const int c1 = bid - 1152;
    float acc = 0.f;
    for (int c = 0; c < 256; ++c) acc += Wk[c * 256 + t] * Wq[c * 256 + c1];
    WKQT[c1 * 256 + t] = acc;
    float v = bk[t] * Wq[t * 256 + c1];
#pragma unroll
    for (int m = 32; m >= 1; m >>= 1) v += __shfl_xor(v, m);
    if ((t & 63) == 0) red[t >> 6] = v;
    __syncthreads();
    if (t == 0) bkq[c1] = red[0] + red[1] + red[2] + red[3];
  } else {
    float acc = 0.f;
    for (int c = 0; c < 256; ++c) acc += Wk[c * 256 + t] * bq[c];
    wkb[t] = acc;
    float v = bk[t] * bq[t];
#pragma unroll
    for (int m = 32; m >= 1; m >>= 1) v += __shfl_xor(v, m);
    if ((t & 63) == 0) red[t >> 6] = v;
    __syncthreads();
    if (t == 0) bkb[0] = red[0] + red[1] + red[2] + red[3];
  }
}

// ---------------------------------------------------------------------------
// kB: blocks 0..127  -> KWQ = (cb@WKQT^T + BKQ)/64 (bf16)
//     blocks 128..639 -> KB[k] = (cb[k].wkb + bkb)/64, 8 rows/block
// ---------------------------------------------------------------------------
__global__ __launch_bounds__(256) void kb_weights(
    const float* __restrict__ cb, const float* __restrict__ WKQT,
    const float* __restrict__ BKQ, unsigned short* __restrict__ KWQ,
    const float* __restrict__ WKB, const float* __restrict__ BKB,
    float* __restrict__ KB) {
  __shared__ __align__(16) char smem[49152];
  const int bid = blockIdx.x, t = threadIdx.x;
  if (bid < 128) {
    gemm_body<true>(smem, cb, WKQT, BKQ, (void*)KWQ, 0.015625f, bid >> 2, bid & 3, t);
  } else {
    const int l32 = t & 31, r = t >> 5;
    const int row = (bid - 128) * 8 + r;
    float acc = 0.f;
#pragma unroll
    for (int j = 0; j < 8; ++j) {
      int c = l32 + j * 32;
      acc += cb[row * 256 + c] * WKB[c];
    }
#pragma unroll
    for (int m = 16; m >= 1; m >>= 1) acc += __shfl_xor(acc, m);
    if (l32 == 0) KB[row] = (acc + BKB[0]) * 0.015625f;
  }
}

// ---------------------------------------------------------------------------
// kC: blocks 0..511    -> quant gather: LDS-tiled transpose of value rows
//     blocks 512..4607 -> logit GEMM, 32x32x16 MFMA (full-line stores)
// ---------------------------------------------------------------------------
__global__ __launch_bounds__(256) void kc_logit_gather(
    const unsigned short* __restrict__ kwq, const unsigned short* __restrict__ lt,
    const float* __restrict__ kb, float* __restrict__ logit_out,
    float* __restrict__ part, const int* __restrict__ code,
    const float* __restrict__ value, float* __restrict__ outq) {
  __shared__ __align__(16) char smem[34816];
  const int bid0 = blockIdx.x, t = threadIdx.x;
  const int lane = t & 63, wave = t >> 6;

  if (bid0 < 512) {
    // ---- quant gather: 32 tokens/block, transpose via padded LDS ----
    float* vt = (float*)smem;            // [32][257]
    int* codes = (int*)(smem + 32896);   // 32 ints
    const int n = bid0 >> 7, s0 = (bid0 & 127) * 32;
    if (t < 32) codes[t] = code[(n << 12) + s0 + t];
    __syncthreads();
#pragma unroll
    for (int j = 0; j < 8; ++j) {
      int jj = wave * 8 + j;
      int idx = codes[jj];
      f32x4 v = *(const f32x4*)(value + (size_t)idx * 256 + lane * 4);
      float* d = vt + jj * 257 + lane * 4;
      d[0] = v[0]; d[1] = v[1]; d[2] = v[2]; d[3] = v[3];
    }
    __syncthreads();
    const int sl = t & 31, cg = t >> 5;  // cg 0..7
#pragma unroll
    for (int ci = 0; ci < 32; ++ci) {
      int c = ci * 8 + cg;
      __builtin_nontemporal_store(vt[sl * 257 + c],
                                  outq + (((size_t)(n * 256 + c)) << 12) + s0 + sl);
    }
    return;
  }

  // ---- logit GEMM (32x32x16) ----
  const int bid = bid0 - 512;
  const int xcd = bid & 7, idx = bid >> 3;
  const int wg = xcd * 512 + idx;
  const int n = wg >> 10, rr = wg & 1023, kt = rr >> 5, st = rr & 31;  // kt-outer
  const int wr = wave >> 1, wc = wave & 1;
  const int l31 = lane & 31, hi = lane >> 5;
  f32x16 acc[2][2] = {};
  const unsigned short* abase = kwq + (size_t)kt * 128 * 256;
  const unsigned short* bbase = lt + ((size_t)n * 4096 + st * 128) * 256;

  auto stage = [&](int kk) {
#pragma unroll
    for (int i = 0; i < 4; ++i) {
      int p0 = (i * 4 + wave) * 64;
      int p = p0 + lane;
      int row = p >> 3, cl = p & 7;
      int goff = row * 256 + kk * 64 + ((cl ^ (row & 7)) * 8);
      gl_lds16(abase + goff, smem + p0 * 16);
      gl_lds16(bbase + goff, smem + 16384 + p0 * 16);
    }
  };

  stage(0);
  for (int kk = 0; kk < 4; ++kk) {
    __syncthreads();  // drains vmcnt -> tile kk visible
#pragma unroll
    for (int kc = 0; kc < 4; ++kc) {  // K=16 chunks within the 64-K tile
      short8 af[2], bf[2];
      const int ch = kc * 2 + hi;     // 8-elem chunk index 0..7
#pragma unroll
      for (int mi = 0; mi < 2; ++mi) {
        int ra = wr * 64 + mi * 32 + l31;
        af[mi] = *(const short8*)(smem + ra * 128 + ((ch ^ (ra & 7)) * 16));
      }
#pragma unroll
      for (int ni = 0; ni < 2; ++ni) {
        int rb = wc * 64 + ni * 32 + l31;
        bf[ni] = *(const short8*)(smem + 16384 + rb * 128 + ((ch ^ (rb & 7)) * 16));
      }
#pragma unroll
      for (int mi = 0; mi < 2; ++mi)
#pragma unroll
        for (int ni = 0; ni < 2; ++ni)
          acc[mi][ni] = __builtin_amdgcn_mfma_f32_32x32x16_bf16(af[mi], bf[ni], acc[mi][ni], 0, 0, 0);
    }
    if (kk < 3) {
      __syncthreads();
      stage(kk + 1);
    }
  }

  // epilogue: D col = lane&31 (32 consecutive s), row = q*8 + hi*4 + e (+tile).
  // Loop order (mi,q,e,ni): consecutive store insts cover the SAME 2 rows,
  // adjacent 32-col halves -> 256B/row sequential, 2 full lines per inst.
  float colsum[2] = {0.f, 0.f};
  float* lbase = logit_out + (size_t)(n * 4096 + kt * 128) * 4096 + st * 128;
#pragma unroll
  for (int mi = 0; mi < 2; ++mi) {
#pragma unroll
    for (int q = 0; q < 4; ++q) {
      int r0 = wr * 64 + mi * 32 + q * 8 + hi * 4;
      f32x4 kbv = *(const f32x4*)(kb + kt * 128 + r0);
#pragma unroll
      for (int e = 0; e < 4; ++e) {
        float* rowp = lbase + (size_t)(r0 + e) * 4096;
#pragma unroll
        for (int ni = 0; ni < 2; ++ni) {
          int cs = wc * 64 + ni * 32 + l31;
          float v = acc[mi][ni][q * 4 + e] + kbv[e];
          __builtin_nontemporal_store(v, rowp + cs);
          colsum[ni] += __expf(v);
        }
      }
    }
  }
  // col cs owned by lanes l and l+32 -> single xor-32 reduce
#pragma unroll
  for (int ni = 0; ni < 2; ++ni) colsum[ni] += __shfl_xor(colsum[ni], 32);
  float* sums = (float*)(smem + 32768);  // [2][128]
  if (lane < 32) {
#pragma unroll
    for (int ni = 0; ni < 2; ++ni)
      sums[wr * 128 + wc * 64 + ni * 32 + l31] = colsum[ni];
  }
  __syncthreads();
  if (t < 128) {
    float tot = sums[t] + sums[128 + t];
    part[((size_t)(n * 32 + kt) << 12) + st * 128 + t] = tot;
  }
}

// ---------------------------------------------------------------------------
// kD: 64 blocks (n, 256-token chunk): partial negLogP (double) per block
// ---------------------------------------------------------------------------
__global__ __launch_bounds__(256) void kd_nlp(const float* __restrict__ part,
                                              const float* __restrict__ logit,
                                              const int* __restrict__ code,
                                              double* __restrict__ part2) {
  const int bid = blockIdx.x, t = threadIdx.x;
  const int n = bid >> 4;
  const int s = ((bid & 15) << 8) + t;
  float se = 0.f;
#pragma unroll
  for (int kt = 0; kt < 32; ++kt) se += part[((size_t)(n * 32 + kt) << 12) + s];
  int cc = code[(n << 12) + s];
  float lc = logit[((size_t)(n * 4096 + cc) << 12) + s];
  double a = (double)logf(se) - (double)lc;
#pragma unroll
  for (int m = 32; m >= 1; m >>= 1) a += __shfl_xor(a, m);
  __shared__ double red[4];
  if ((t & 63) == 0) red[t >> 6] = a;
  __syncthreads();
  if (t == 0) part2[bid] = red[0] + red[1] + red[2] + red[3];
}

// ---------------------------------------------------------------------------
// kE: final reduce, 1 block of 64: outn[n] = sum of 16 partials
// ---------------------------------------------------------------------------
__global__ __launch_bounds__(64) void ke_final(const double* __restrict__ part2,
                                               float* __restrict__ outn) {
  const int t = threadIdx.x;
  const int n = t >> 4, i = t & 15;
  double v = part2[n * 16 + i];
#pragma unroll
  for (int m = 8; m >= 1; m >>= 1) v += __shfl_xor(v, m);
  if (i == 0) outn[n] = (float)v;
}

// ---------------------------------------------------------------------------
extern "C" void kernel_launch(void* const* d_in, const int* in_sizes, int n_in,
                              void* d_out, int out_size, void* d_ws, size_t ws_size,
                              hipStream_t stream) {
  const float* latent = (const float*)d_in[0];
  const int* code = (const int*)d_in[1];
  const float* cb = (const float*)d_in[2];
  const float* Wq = (const float*)d_in[3];
  const float* bq = (const float*)d_in[4];
  const float* Wk = (const float*)d_in[5];
  const float* bk = (const float*)d_in[6];
  const float* Wv = (const float*)d_in[7];
  const float* bv = (const float*)d_in[8];

  float* out = (float*)d_out;
  float* outq = out;                // 4*256*4096
  float* outl = out + 4194304;      // 4*4096*4096
  float* outn = out + 71303168;     // 4

  char* ws = (char*)d_ws;
  unsigned short* LT = (unsigned short*)(ws + 0);         // 8 MB  bf16 (n,s,c)
  unsigned short* KWQ = (unsigned short*)(ws + 8388608);  // 2 MB  bf16 (k,c)
  float* KB = (float*)(ws + 10485760);                    // 16 KB
  float* VALUE = (float*)(ws + 10502144);                 // 4 MB  f32 (k,c)
  float* PART = (float*)(ws + 14696448);                  // 2 MB  f32 (n,32,s)
  float* WKQT = (float*)(ws + 16793600);                  // 256 KB
  float* BKQ = (float*)(ws + 17055744);                   // 1 KB
  float* WKB = (float*)(ws + 17056768);                   // 1 KB
  float* BKB = (float*)(ws + 17057792);                   // 4 B
  double* PART2 = (double*)(ws + 17058816);               // 512 B

  ka_trans_pre<<<1409, 256, 0, stream>>>(latent, LT, Wq, bq, Wk, bk, WKQT, BKQ,
                                         WKB, BKB, cb, Wv, bv, VALUE);
  kb_weights<<<640, 256, 0, stream>>>(cb, WKQT, BKQ, KWQ, WKB, BKB, KB);
  kc_logit_gather<<<4608, 256, 0, stream>>>(KWQ, LT, KB, outl, PART, code, VALUE, outq);
  kd_nlp<<<64, 256, 0, stream>>>(PART, outl, code, PART2);
  ke_final<<<1, 64, 0, stream>>>(PART2, outn);
}